// Round 4
// baseline (561.225 us; speedup 1.0000x reference)
//
#include <hip/hip_runtime.h>

// ---------------- constants ----------------
#define HEADS 6
#define DIM 192
#define DH 32
#define PW 144            // tokens per window
#define WN 960            // windows
#define MWD 15            // MW
#define SCALE 0.17677669529663687f

typedef __attribute__((ext_vector_type(8))) short bf16x8;
typedef __attribute__((ext_vector_type(4))) short bf16x4;
typedef __attribute__((ext_vector_type(4))) float f32x4;

#define MFMA16(a,b,c) __builtin_amdgcn_mfma_f32_16x16x32_bf16(a,b,c,0,0,0)

__device__ __forceinline__ unsigned short f2bf(float f) {
    unsigned int u = __builtin_bit_cast(unsigned int, f);
    u += 0x7fffu + ((u >> 16) & 1u);
    return (unsigned short)(u >> 16);
}
__device__ __forceinline__ float bf2f(unsigned short s) {
    unsigned int u = ((unsigned int)s) << 16;
    return __builtin_bit_cast(float, u);
}

// ---------------- P1: weight transpose + bf16 ----------------
__global__ void prep_weights(const float* __restrict__ wqkv,
                             const float* __restrict__ wproj,
                             unsigned short* __restrict__ wqkvT,
                             unsigned short* __restrict__ wprojT) {
    int t = blockIdx.x * 256 + threadIdx.x;     // 147456 total
    if (t < 576 * 192) {
        int n = t / 192, k = t % 192;
        wqkvT[t] = f2bf(wqkv[k * 576 + n]);
    } else {
        int t2 = t - 576 * 192;                 // < 36864
        int n = t2 / 192, k = t2 % 192;
        wprojT[t2] = f2bf(wproj[k * 192 + n]);
    }
}

// ---------------- P2: bias in MFMA C-fragment order ----------------
// biasR[(((wt*6+h)*9 + it)*64 + lane)*40 + (ct*4+r)]  (e>=36 pad = 0)
// lane = quad*16+l16 ; i = it*16+quad*4+r ; j = ct*16+l16
// grid 34560 x 256 = 8,847,360 exact.
__global__ __launch_bounds__(256) void prep_biasR(const float* __restrict__ table,
                                                  unsigned short* __restrict__ biasR) {
    int t = blockIdx.x * 256 + threadIdx.x;
    int e = t % 40;
    int u = t / 40;
    int lane = u & 63;
    int u2 = u >> 6;
    int it = u2 % 9;
    int u3 = u2 / 9;
    int h = u3 % 6;
    int wt = u3 / 6;
    unsigned short v = 0;
    if (e < 36) {
        int ct = e >> 2, r = e & 3;
        int quad = lane >> 4, l16 = lane & 15;
        int i = it * 16 + quad * 4 + r;
        int j = ct * 16 + l16;
        int z1 = i / 72, h1 = (i / 12) % 6, w1 = i % 12;
        int z2 = j / 72, h2 = (j / 12) % 6, w2 = j % 12;
        int pos = (z1 + 2 * z2) * 828 + (h1 + 6 * h2) * 23 + (w1 - w2 + 11);
        v = f2bf(table[pos * 384 + wt * 6 + h]);
    }
    biasR[t] = v;
}

// ---------------- P3: mask in MFMA C-fragment order (bf16) ----------------
// maskR[((win*9 + it)*64 + lane)*40 + (ct*4+r)]
// grid 86400 x 256 = 22,118,400 exact.
__global__ __launch_bounds__(256) void prep_maskR(const float* __restrict__ mask,
                                                  unsigned short* __restrict__ maskR) {
    int t = blockIdx.x * 256 + threadIdx.x;
    int e = t % 40;
    int u = t / 40;
    int lane = u & 63;
    int u2 = u >> 6;
    int it = u2 % 9;
    int win = u2 / 9;
    unsigned short v = 0;
    if (e < 36) {
        int ct = e >> 2, r = e & 3;
        int quad = lane >> 4, l16 = lane & 15;
        int i = it * 16 + quad * 4 + r;
        int j = ct * 16 + l16;
        v = f2bf(mask[win * 20736 + i * 144 + j]);
    }
    maskR[t] = v;
}

// ---------------- K1: qkv = x @ w_qkv (fp32->bf16 fused in staging) ----------------
// grid 12960 (swizzled: 2160 mtiles x 6 nblk), block 256 (4 waves).
// BM=64, BN=96, K=192. LDS = 64,000 B. XCD swizzle keeps the 6x x-tile
// re-read L2-local, so fusing the fp32 read here costs no extra HBM.
__global__ __launch_bounds__(256) void qkv_gemm(
        const float* __restrict__ x, const unsigned short* __restrict__ wqkvT,
        unsigned short* __restrict__ qb, unsigned short* __restrict__ kb,
        unsigned short* __restrict__ vtb) {
    __shared__ unsigned short A[64 * 200];
    __shared__ unsigned short Bt[96 * 200];
    int bid = blockIdx.x;
    int r8 = bid & 7, s = bid >> 3;          // s < 1620
    int nblk = s % 6;
    int mtile = r8 * 270 + s / 6;            // 0..2159
    int tid = threadIdx.x;

    // stage A: 64x192 fp32 -> bf16 (3072 f32x4 chunks)
    const float* xp = x + (long long)mtile * (64 * 192);
    #pragma unroll
    for (int it = 0; it < 12; ++it) {
        int c = tid + it * 256;
        int row = c / 48, c4 = c % 48;
        f32x4 v = *(const f32x4*)(xp + row * 192 + c4 * 4);
        bf16x4 o;
        o[0] = (short)f2bf(v[0]); o[1] = (short)f2bf(v[1]);
        o[2] = (short)f2bf(v[2]); o[3] = (short)f2bf(v[3]);
        *(bf16x4*)&A[row * 200 + c4 * 4] = o;
    }
    // stage Bt: rows [nblk*96, +96) of wqkvT = 2304 chunks
    const unsigned short* wp = wqkvT + nblk * (96 * 192);
    #pragma unroll
    for (int it = 0; it < 9; ++it) {
        int c = tid + it * 256;
        int row = c / 24, c8 = (c % 24) * 8;
        *(bf16x8*)&Bt[row * 200 + c8] = *(const bf16x8*)(wp + c * 8);
    }
    __syncthreads();

    int lane = tid & 63, wv = tid >> 6;
    int l16 = lane & 15, quad = lane >> 4;
    f32x4 acc[6];
    #pragma unroll
    for (int i = 0; i < 6; ++i) acc[i] = (f32x4){0.f, 0.f, 0.f, 0.f};

    #pragma unroll
    for (int kc = 0; kc < 6; ++kc) {
        bf16x8 af = *(const bf16x8*)&A[(wv * 16 + l16) * 200 + kc * 32 + quad * 8];
        #pragma unroll
        for (int ct = 0; ct < 6; ++ct) {
            bf16x8 bfr = *(const bf16x8*)&Bt[(ct * 16 + l16) * 200 + kc * 32 + quad * 8];
            acc[ct] = MFMA16(af, bfr, acc[ct]);
        }
    }

    int token0 = mtile * 64 + wv * 16 + quad * 4;
    int win = token0 / 144;
    int p0 = token0 - win * 144;
    #pragma unroll
    for (int ct = 0; ct < 6; ++ct) {
        int c0 = nblk * 96 + ct * 16;
        int which = c0 / 192;
        int head = (c0 % 192) / 32;
        int d = (c0 % 32) + l16;
        if (which == 0) {
            int base = ((win * 6 + head) * 144 + p0) * 32 + d;
            #pragma unroll
            for (int r = 0; r < 4; ++r) qb[base + r * 32] = f2bf(acc[ct][r]);
        } else if (which == 1) {
            int base = ((win * 6 + head) * 144 + p0) * 32 + d;
            #pragma unroll
            for (int r = 0; r < 4; ++r) kb[base + r * 32] = f2bf(acc[ct][r]);
        } else {
            int base = ((win * 6 + head) * 32 + d) * 144 + p0;   // transposed
            bf16x4 o;
            #pragma unroll
            for (int r = 0; r < 4; ++r) o[r] = (short)f2bf(acc[ct][r]);
            *(bf16x4*)&vtb[base] = o;
        }
    }
}

// ---------------- K2: attention per (window, head) ----------------
// grid 5760 swizzled (6 heads of a window share an XCD); block 192 (3 waves).
// Q fragments load straight from global (coalesced 1KB/wave) -> no Q LDS.
// LDS = K 11,520 + Vt 10,240 + Pl 16,128 = 37,888 B -> 4 blocks/CU.
// Bias+mask come pre-arranged in C-fragment order: 10 bf16x8 loads per rt
// replace 72 scalar loads. launch_bounds(192,4) caps VGPR at 128 so VGPRs
// don't undercut the 4-block LDS occupancy.
__global__ __launch_bounds__(192, 4) void attn(
        const unsigned short* __restrict__ qb, const unsigned short* __restrict__ kb,
        const unsigned short* __restrict__ vtb, const unsigned short* __restrict__ biasR,
        const unsigned short* __restrict__ maskR, unsigned short* __restrict__ Ob) {
    __shared__ unsigned short Kl[144 * 40];
    __shared__ unsigned short Vt[32 * 160];
    __shared__ unsigned short Pl[3 * 16 * 168];

    int bx = blockIdx.x;
    int r8 = bx & 7, s = bx >> 3;            // s < 720
    int h = s % 6;
    int win = r8 * 120 + s / 6;
    int wt = win / MWD;
    int tid = threadIdx.x;
    int lane = tid & 63, wv = tid >> 6;
    int l16 = lane & 15, quad = lane >> 4;

    int qoff = (win * 6 + h) * (144 * 32);
    #pragma unroll
    for (int it = 0; it < 3; ++it) {
        int c = tid + it * 192;
        int row = c >> 2, c8 = (c & 3) * 8;
        *(bf16x8*)&Kl[row * 40 + c8] = *(const bf16x8*)(kb + qoff + c * 8);
        int vr = c / 18, vc = (c % 18) * 8;
        *(bf16x8*)&Vt[vr * 160 + vc] = *(const bf16x8*)(vtb + qoff + c * 8);
    }
    // zero P pad cols [144,160) of this wave's tile
    {
        int row = lane >> 2, ch = lane & 3;
        *(bf16x4*)&Pl[wv * 2688 + row * 168 + 144 + ch * 4] = (bf16x4){0, 0, 0, 0};
    }
    // zero Vt pad cols [144,160)
    if (tid < 64) {
        int row = tid >> 1, off = 144 + (tid & 1) * 8;
        *(bf16x8*)&Vt[row * 160 + off] = (bf16x8){0, 0, 0, 0, 0, 0, 0, 0};
    }
    __syncthreads();

    const unsigned short* bR = biasR + ((wt * 6 + h) * 9) * 2560 + lane * 40;
    const unsigned short* mR = maskR + (win * 9) * 2560 + lane * 40;
    const f32x4 z = {0.f, 0.f, 0.f, 0.f};

    for (int rt = 0; rt < 3; ++rt) {
        int it = wv * 3 + rt;
        int i0 = it * 16;
        // Q fragment direct from global
        bf16x8 aq = *(const bf16x8*)(qb + qoff + (i0 + l16) * 32 + quad * 8);
        // bias+mask fragment loads (issued early, consumed after MFMAs)
        bf16x8 bb[5], mm[5];
        #pragma unroll
        for (int w = 0; w < 5; ++w) {
            bb[w] = *(const bf16x8*)(bR + it * 2560 + w * 8);
            mm[w] = *(const bf16x8*)(mR + it * 2560 + w * 8);
        }
        f32x4 sreg[9];
        #pragma unroll
        for (int ct = 0; ct < 9; ++ct) {
            bf16x8 bk = *(const bf16x8*)&Kl[(ct * 16 + l16) * 40 + quad * 8];
            sreg[ct] = MFMA16(aq, bk, z);
        }
        #pragma unroll
        for (int ct = 0; ct < 9; ++ct) {
            #pragma unroll
            for (int r = 0; r < 4; ++r) {
                int e = ct * 4 + r;
                sreg[ct][r] = sreg[ct][r] * SCALE
                            + bf2f((unsigned short)bb[e >> 3][e & 7])
                            + bf2f((unsigned short)mm[e >> 3][e & 7]);
            }
        }
        #pragma unroll
        for (int r = 0; r < 4; ++r) {
            float mx = sreg[0][r];
            #pragma unroll
            for (int ct = 1; ct < 9; ++ct) mx = fmaxf(mx, sreg[ct][r]);
            #pragma unroll
            for (int off = 1; off < 16; off <<= 1) mx = fmaxf(mx, __shfl_xor(mx, off, 64));
            float sum = 0.f;
            #pragma unroll
            for (int ct = 0; ct < 9; ++ct) { float e = __expf(sreg[ct][r] - mx); sreg[ct][r] = e; sum += e; }
            #pragma unroll
            for (int off = 1; off < 16; off <<= 1) sum += __shfl_xor(sum, off, 64);
            float inv = 1.0f / sum;
            #pragma unroll
            for (int ct = 0; ct < 9; ++ct) sreg[ct][r] *= inv;
        }
        int pb = wv * 2688;
        #pragma unroll
        for (int ct = 0; ct < 9; ++ct) {
            #pragma unroll
            for (int r = 0; r < 4; ++r)
                Pl[pb + (quad * 4 + r) * 168 + ct * 16 + l16] = f2bf(sreg[ct][r]);
        }
        f32x4 o0 = z, o1 = z;
        #pragma unroll
        for (int kc = 0; kc < 5; ++kc) {
            bf16x8 ap = *(const bf16x8*)&Pl[pb + l16 * 168 + kc * 32 + quad * 8];
            bf16x8 b0 = *(const bf16x8*)&Vt[l16 * 160 + kc * 32 + quad * 8];
            bf16x8 b1 = *(const bf16x8*)&Vt[(16 + l16) * 160 + kc * 32 + quad * 8];
            o0 = MFMA16(ap, b0, o0);
            o1 = MFMA16(ap, b1, o1);
        }
        #pragma unroll
        for (int r = 0; r < 4; ++r) {
            int i = i0 + quad * 4 + r;
            int ob = (win * 144 + i) * 192 + h * 32 + l16;
            Ob[ob] = f2bf(o0[r]);
            Ob[ob + 16] = f2bf(o1[r]);
        }
    }
}

// ---------------- K3: out = O @ w_proj + b_proj (fp32 out) ----------------
// grid 4320 (swizzled: 2160 mtiles x 2 nblk), block 256. BM=64, BN=96, K=192.
__global__ __launch_bounds__(256) void out_gemm(
        const unsigned short* __restrict__ Ob, const unsigned short* __restrict__ wprojT,
        const float* __restrict__ bproj, float* __restrict__ out) {
    __shared__ unsigned short A[64 * 200];
    __shared__ unsigned short Bt[96 * 200];
    int bid = blockIdx.x;
    int r8 = bid & 7, s = bid >> 3;          // s < 540
    int nblk = s % 2;
    int mtile = r8 * 270 + s / 2;            // 0..2159
    int tid = threadIdx.x;

    const unsigned short* op = Ob + (long long)mtile * (64 * 192);
    #pragma unroll
    for (int it = 0; it < 6; ++it) {
        int c = tid + it * 256;
        int row = c / 24, c8 = (c % 24) * 8;
        *(bf16x8*)&A[row * 200 + c8] = *(const bf16x8*)(op + c * 8);
    }
    const unsigned short* wp = wprojT + nblk * (96 * 192);
    #pragma unroll
    for (int it = 0; it < 9; ++it) {
        int c = tid + it * 256;
        int row = c / 24, c8 = (c % 24) * 8;
        *(bf16x8*)&Bt[row * 200 + c8] = *(const bf16x8*)(wp + c * 8);
    }
    __syncthreads();

    int lane = tid & 63, wv = tid >> 6;
    int l16 = lane & 15, quad = lane >> 4;
    f32x4 acc[6];
    #pragma unroll
    for (int i = 0; i < 6; ++i) acc[i] = (f32x4){0.f, 0.f, 0.f, 0.f};
    #pragma unroll
    for (int kc = 0; kc < 6; ++kc) {
        bf16x8 af = *(const bf16x8*)&A[(wv * 16 + l16) * 200 + kc * 32 + quad * 8];
        #pragma unroll
        for (int ct = 0; ct < 6; ++ct) {
            bf16x8 bfr = *(const bf16x8*)&Bt[(ct * 16 + l16) * 200 + kc * 32 + quad * 8];
            acc[ct] = MFMA16(af, bfr, acc[ct]);
        }
    }
    int token0 = mtile * 64 + wv * 16 + quad * 4;
    #pragma unroll
    for (int ct = 0; ct < 6; ++ct) {
        int c = nblk * 96 + ct * 16 + l16;
        float bp = bproj[c];
        #pragma unroll
        for (int r = 0; r < 4; ++r)
            out[(token0 + r) * 192 + c] = acc[ct][r] + bp;
    }
}

// ---------------- launch ----------------
extern "C" void kernel_launch(void* const* d_in, const int* in_sizes, int n_in,
                              void* d_out, int out_size, void* d_ws, size_t ws_size,
                              hipStream_t stream) {
    const float* x     = (const float*)d_in[0];
    const float* mask  = (const float*)d_in[1];
    const float* wqkv  = (const float*)d_in[2];
    const float* wproj = (const float*)d_in[3];
    const float* bproj = (const float*)d_in[4];
    const float* btab  = (const float*)d_in[5];
    float* out = (float*)d_out;

    char* ws = (char*)d_ws;
    // ws layout (bytes):
    unsigned short* Ob     = (unsigned short*)(ws + 0);            // 53,084,160
    unsigned short* qb     = (unsigned short*)(ws + 53084160);     // 53,084,160
    unsigned short* kb     = (unsigned short*)(ws + 106168320);    // 53,084,160
    unsigned short* vtb    = (unsigned short*)(ws + 159252480);    // 53,084,160
    unsigned short* biasR  = (unsigned short*)(ws + 212336640);    // 17,694,720
    unsigned short* maskR  = (unsigned short*)(ws + 230031360);    // 44,236,800
    unsigned short* wqkvT  = (unsigned short*)(ws + 274268160);    //    221,184
    unsigned short* wprojT = (unsigned short*)(ws + 274489344);    //     73,728
    // total: 274,563,072 bytes

    prep_weights<<<576, 256, 0, stream>>>(wqkv, wproj, wqkvT, wprojT);
    prep_biasR<<<34560, 256, 0, stream>>>(btab, biasR);
    prep_maskR<<<86400, 256, 0, stream>>>(mask, maskR);
    qkv_gemm<<<12960, 256, 0, stream>>>(x, wqkvT, qb, kb, vtb);
    attn<<<5760, 192, 0, stream>>>(qb, kb, vtb, biasR, maskR, Ob);
    out_gemm<<<4320, 256, 0, stream>>>(Ob, wprojT, bproj, out);
}

// Round 5
// 560.143 us; speedup vs baseline: 1.0019x; 1.0019x over previous
//
#include <hip/hip_runtime.h>

// ---------------- constants ----------------
#define HEADS 6
#define DIM 192
#define DH 32
#define PW 144            // tokens per window
#define WN 960            // windows
#define MWD 15            // MW
#define SCALE 0.17677669529663687f

typedef __attribute__((ext_vector_type(8))) short bf16x8;
typedef __attribute__((ext_vector_type(4))) short bf16x4;
typedef __attribute__((ext_vector_type(4))) float f32x4;

#define MFMA16(a,b,c) __builtin_amdgcn_mfma_f32_16x16x32_bf16(a,b,c,0,0,0)

__device__ __forceinline__ unsigned short f2bf(float f) {
    unsigned int u = __builtin_bit_cast(unsigned int, f);
    u += 0x7fffu + ((u >> 16) & 1u);
    return (unsigned short)(u >> 16);
}
__device__ __forceinline__ float bf2f(unsigned short s) {
    unsigned int u = ((unsigned int)s) << 16;
    return __builtin_bit_cast(float, u);
}

// ---------------- P1: weight transpose + bf16 ----------------
__global__ void prep_weights(const float* __restrict__ wqkv,
                             const float* __restrict__ wproj,
                             unsigned short* __restrict__ wqkvT,
                             unsigned short* __restrict__ wprojT) {
    int t = blockIdx.x * 256 + threadIdx.x;     // 147456 total
    if (t < 576 * 192) {
        int n = t / 192, k = t % 192;
        wqkvT[t] = f2bf(wqkv[k * 576 + n]);
    } else {
        int t2 = t - 576 * 192;                 // < 36864
        int n = t2 / 192, k = t2 % 192;
        wprojT[t2] = f2bf(wproj[k * 192 + n]);
    }
}

// ---------------- P2: bias in MFMA C-fragment order ----------------
// biasR[(((wt*6+h)*9 + it)*64 + lane)*40 + (ct*4+r)]  (e>=36 pad = 0)
// grid 34560 x 256 = 8,847,360 exact.
__global__ __launch_bounds__(256) void prep_biasR(const float* __restrict__ table,
                                                  unsigned short* __restrict__ biasR) {
    int t = blockIdx.x * 256 + threadIdx.x;
    int e = t % 40;
    int u = t / 40;
    int lane = u & 63;
    int u2 = u >> 6;
    int it = u2 % 9;
    int u3 = u2 / 9;
    int h = u3 % 6;
    int wt = u3 / 6;
    unsigned short v = 0;
    if (e < 36) {
        int ct = e >> 2, r = e & 3;
        int quad = lane >> 4, l16 = lane & 15;
        int i = it * 16 + quad * 4 + r;
        int j = ct * 16 + l16;
        int z1 = i / 72, h1 = (i / 12) % 6, w1 = i % 12;
        int z2 = j / 72, h2 = (j / 12) % 6, w2 = j % 12;
        int pos = (z1 + 2 * z2) * 828 + (h1 + 6 * h2) * 23 + (w1 - w2 + 11);
        v = f2bf(table[pos * 384 + wt * 6 + h]);
    }
    biasR[t] = v;
}

// ---------------- P3: mask -> MFMA C-fragment order (bf16), LDS-tiled ----------------
// One block per (win, it): coalesced fp32 read of 16x144 tile -> LDS ->
// coalesced bf16 fragment-order write. grid 8640 x 256.
__global__ __launch_bounds__(256) void prep_maskR(const float* __restrict__ mask,
                                                  unsigned short* __restrict__ maskR) {
    __shared__ float M[16 * 144];      // 9216 B
    int b = blockIdx.x;                // 960*9
    int win = b / 9, it = b % 9;
    int tid = threadIdx.x;
    const float* mp = mask + win * 20736 + it * (16 * 144);
    #pragma unroll
    for (int k = 0; k < 9; ++k) M[tid + k * 256] = mp[tid + k * 256];
    __syncthreads();
    unsigned short* op = maskR + (long long)((win * 9 + it) * 64) * 40;
    #pragma unroll
    for (int k = 0; k < 10; ++k) {
        int t = tid + k * 256;         // 2560 = 64 lanes * 40
        int e = t % 40, lane = t / 40;
        unsigned short v = 0;
        if (e < 36) {
            int ct = e >> 2, r = e & 3;
            int quad = lane >> 4, l16 = lane & 15;
            v = f2bf(M[(quad * 4 + r) * 144 + ct * 16 + l16]);
        }
        op[t] = v;
    }
}

// ---------------- K1: qkv = x @ w_qkv, A-fragments direct from global ----------------
// grid 12960 (swizzled: 2160 mtiles x 6 nblk), block 256 (4 waves).
// BM=64, BN=96, K=192. Only Bt in LDS (38,400 B) -> 4 blocks/CU, 16 waves.
// A fragment = 8 consecutive k of one x row: 2 f32x4 global loads + in-reg cvt.
__global__ __launch_bounds__(256, 4) void qkv_gemm(
        const float* __restrict__ x, const unsigned short* __restrict__ wqkvT,
        unsigned short* __restrict__ qb, unsigned short* __restrict__ kb,
        unsigned short* __restrict__ vtb) {
    __shared__ unsigned short Bt[96 * 200];
    int bid = blockIdx.x;
    int r8 = bid & 7, s = bid >> 3;          // s < 1620
    int nblk = s % 6;
    int mtile = r8 * 270 + s / 6;            // 0..2159
    int tid = threadIdx.x;
    int lane = tid & 63, wv = tid >> 6;
    int l16 = lane & 15, quad = lane >> 4;

    // stage Bt: rows [nblk*96, +96) of wqkvT = 2304 chunks
    const unsigned short* wp = wqkvT + nblk * (96 * 192);
    #pragma unroll
    for (int it = 0; it < 9; ++it) {
        int c = tid + it * 256;
        int row = c / 24, c8 = (c % 24) * 8;
        *(bf16x8*)&Bt[row * 200 + c8] = *(const bf16x8*)(wp + c * 8);
    }

    // A fragments direct from global (issued before barrier; don't depend on LDS)
    const float* xrow = x + (long long)(mtile * 64 + wv * 16 + l16) * 192 + quad * 8;
    bf16x8 afr[6];
    #pragma unroll
    for (int kc = 0; kc < 6; ++kc) {
        f32x4 v0 = *(const f32x4*)(xrow + kc * 32);
        f32x4 v1 = *(const f32x4*)(xrow + kc * 32 + 4);
        bf16x8 o;
        o[0] = (short)f2bf(v0[0]); o[1] = (short)f2bf(v0[1]);
        o[2] = (short)f2bf(v0[2]); o[3] = (short)f2bf(v0[3]);
        o[4] = (short)f2bf(v1[0]); o[5] = (short)f2bf(v1[1]);
        o[6] = (short)f2bf(v1[2]); o[7] = (short)f2bf(v1[3]);
        afr[kc] = o;
    }
    __syncthreads();

    f32x4 acc[6];
    #pragma unroll
    for (int i = 0; i < 6; ++i) acc[i] = (f32x4){0.f, 0.f, 0.f, 0.f};
    #pragma unroll
    for (int kc = 0; kc < 6; ++kc) {
        #pragma unroll
        for (int ct = 0; ct < 6; ++ct) {
            bf16x8 bfr = *(const bf16x8*)&Bt[(ct * 16 + l16) * 200 + kc * 32 + quad * 8];
            acc[ct] = MFMA16(afr[kc], bfr, acc[ct]);
        }
    }

    int token0 = mtile * 64 + wv * 16 + quad * 4;
    int win = token0 / 144;
    int p0 = token0 - win * 144;
    #pragma unroll
    for (int ct = 0; ct < 6; ++ct) {
        int c0 = nblk * 96 + ct * 16;
        int which = c0 / 192;
        int head = (c0 % 192) / 32;
        int d = (c0 % 32) + l16;
        if (which == 0) {
            int base = ((win * 6 + head) * 144 + p0) * 32 + d;
            #pragma unroll
            for (int r = 0; r < 4; ++r) qb[base + r * 32] = f2bf(acc[ct][r]);
        } else if (which == 1) {
            int base = ((win * 6 + head) * 144 + p0) * 32 + d;
            #pragma unroll
            for (int r = 0; r < 4; ++r) kb[base + r * 32] = f2bf(acc[ct][r]);
        } else {
            int base = ((win * 6 + head) * 32 + d) * 144 + p0;   // transposed
            bf16x4 o;
            #pragma unroll
            for (int r = 0; r < 4; ++r) o[r] = (short)f2bf(acc[ct][r]);
            *(bf16x4*)&vtb[base] = o;
        }
    }
}

// ---------------- K2: attention per (window, head) ----------------
// grid 5760 swizzled (6 heads of a window share an XCD); block 192 (3 waves).
// LDS 37,888 B -> 4 blocks/CU = 3 waves/SIMD; launch_bounds(192,3) (VGPR cap
// ~170) -- the round-4 (192,4)/128-cap risked spills for occupancy LDS can't
// deliver anyway.
__global__ __launch_bounds__(192, 3) void attn(
        const unsigned short* __restrict__ qb, const unsigned short* __restrict__ kb,
        const unsigned short* __restrict__ vtb, const unsigned short* __restrict__ biasR,
        const unsigned short* __restrict__ maskR, unsigned short* __restrict__ Ob) {
    __shared__ unsigned short Kl[144 * 40];
    __shared__ unsigned short Vt[32 * 160];
    __shared__ unsigned short Pl[3 * 16 * 168];

    int bx = blockIdx.x;
    int r8 = bx & 7, s = bx >> 3;            // s < 720
    int h = s % 6;
    int win = r8 * 120 + s / 6;
    int wt = win / MWD;
    int tid = threadIdx.x;
    int lane = tid & 63, wv = tid >> 6;
    int l16 = lane & 15, quad = lane >> 4;

    int qoff = (win * 6 + h) * (144 * 32);
    #pragma unroll
    for (int it = 0; it < 3; ++it) {
        int c = tid + it * 192;
        int row = c >> 2, c8 = (c & 3) * 8;
        *(bf16x8*)&Kl[row * 40 + c8] = *(const bf16x8*)(kb + qoff + c * 8);
        int vr = c / 18, vc = (c % 18) * 8;
        *(bf16x8*)&Vt[vr * 160 + vc] = *(const bf16x8*)(vtb + qoff + c * 8);
    }
    // zero P pad cols [144,160) of this wave's tile
    {
        int row = lane >> 2, ch = lane & 3;
        *(bf16x4*)&Pl[wv * 2688 + row * 168 + 144 + ch * 4] = (bf16x4){0, 0, 0, 0};
    }
    // zero Vt pad cols [144,160)
    if (tid < 64) {
        int row = tid >> 1, off = 144 + (tid & 1) * 8;
        *(bf16x8*)&Vt[row * 160 + off] = (bf16x8){0, 0, 0, 0, 0, 0, 0, 0};
    }
    __syncthreads();

    const unsigned short* bR = biasR + (long long)((wt * 6 + h) * 9) * 2560 + lane * 40;
    const unsigned short* mR = maskR + (long long)(win * 9) * 2560 + lane * 40;
    const f32x4 z = {0.f, 0.f, 0.f, 0.f};

    for (int rt = 0; rt < 3; ++rt) {
        int it = wv * 3 + rt;
        int i0 = it * 16;
        // Q fragment direct from global
        bf16x8 aq = *(const bf16x8*)(qb + qoff + (i0 + l16) * 32 + quad * 8);
        // bias+mask fragment loads (issued early, consumed after MFMAs)
        bf16x8 bb[5], mm[5];
        #pragma unroll
        for (int w = 0; w < 5; ++w) {
            bb[w] = *(const bf16x8*)(bR + it * 2560 + w * 8);
            mm[w] = *(const bf16x8*)(mR + it * 2560 + w * 8);
        }
        f32x4 sreg[9];
        #pragma unroll
        for (int ct = 0; ct < 9; ++ct) {
            bf16x8 bk = *(const bf16x8*)&Kl[(ct * 16 + l16) * 40 + quad * 8];
            sreg[ct] = MFMA16(aq, bk, z);
        }
        #pragma unroll
        for (int ct = 0; ct < 9; ++ct) {
            #pragma unroll
            for (int r = 0; r < 4; ++r) {
                int e = ct * 4 + r;
                sreg[ct][r] = sreg[ct][r] * SCALE
                            + bf2f((unsigned short)bb[e >> 3][e & 7])
                            + bf2f((unsigned short)mm[e >> 3][e & 7]);
            }
        }
        #pragma unroll
        for (int r = 0; r < 4; ++r) {
            float mx = sreg[0][r];
            #pragma unroll
            for (int ct = 1; ct < 9; ++ct) mx = fmaxf(mx, sreg[ct][r]);
            #pragma unroll
            for (int off = 1; off < 16; off <<= 1) mx = fmaxf(mx, __shfl_xor(mx, off, 64));
            float sum = 0.f;
            #pragma unroll
            for (int ct = 0; ct < 9; ++ct) { float e = __expf(sreg[ct][r] - mx); sreg[ct][r] = e; sum += e; }
            #pragma unroll
            for (int off = 1; off < 16; off <<= 1) sum += __shfl_xor(sum, off, 64);
            float inv = 1.0f / sum;
            #pragma unroll
            for (int ct = 0; ct < 9; ++ct) sreg[ct][r] *= inv;
        }
        int pb = wv * 2688;
        #pragma unroll
        for (int ct = 0; ct < 9; ++ct) {
            #pragma unroll
            for (int r = 0; r < 4; ++r)
                Pl[pb + (quad * 4 + r) * 168 + ct * 16 + l16] = f2bf(sreg[ct][r]);
        }
        f32x4 o0 = z, o1 = z;
        #pragma unroll
        for (int kc = 0; kc < 5; ++kc) {
            bf16x8 ap = *(const bf16x8*)&Pl[pb + l16 * 168 + kc * 32 + quad * 8];
            bf16x8 b0 = *(const bf16x8*)&Vt[l16 * 160 + kc * 32 + quad * 8];
            bf16x8 b1 = *(const bf16x8*)&Vt[(16 + l16) * 160 + kc * 32 + quad * 8];
            o0 = MFMA16(ap, b0, o0);
            o1 = MFMA16(ap, b1, o1);
        }
        #pragma unroll
        for (int r = 0; r < 4; ++r) {
            int i = i0 + quad * 4 + r;
            int ob = (win * 144 + i) * 192 + h * 32 + l16;
            Ob[ob] = f2bf(o0[r]);
            Ob[ob + 16] = f2bf(o1[r]);
        }
    }
}

// ---------------- K3: out = O @ w_proj + b_proj, A-fragments direct ----------------
// grid 4320 (swizzled: 2160 mtiles x 2 nblk), block 256. Only Bt in LDS
// (38,400 B) -> 4 blocks/CU. A fragment = 16B contiguous bf16 load from Ob.
__global__ __launch_bounds__(256, 4) void out_gemm(
        const unsigned short* __restrict__ Ob, const unsigned short* __restrict__ wprojT,
        const float* __restrict__ bproj, float* __restrict__ out) {
    __shared__ unsigned short Bt[96 * 200];
    int bid = blockIdx.x;
    int r8 = bid & 7, s = bid >> 3;          // s < 540
    int nblk = s % 2;
    int mtile = r8 * 270 + s / 2;            // 0..2159
    int tid = threadIdx.x;
    int lane = tid & 63, wv = tid >> 6;
    int l16 = lane & 15, quad = lane >> 4;

    const unsigned short* wp = wprojT + nblk * (96 * 192);
    #pragma unroll
    for (int it = 0; it < 9; ++it) {
        int c = tid + it * 256;
        int row = c / 24, c8 = (c % 24) * 8;
        *(bf16x8*)&Bt[row * 200 + c8] = *(const bf16x8*)(wp + c * 8);
    }

    const unsigned short* orow = Ob + (long long)(mtile * 64 + wv * 16 + l16) * 192 + quad * 8;
    bf16x8 afr[6];
    #pragma unroll
    for (int kc = 0; kc < 6; ++kc) afr[kc] = *(const bf16x8*)(orow + kc * 32);
    __syncthreads();

    f32x4 acc[6];
    #pragma unroll
    for (int i = 0; i < 6; ++i) acc[i] = (f32x4){0.f, 0.f, 0.f, 0.f};
    #pragma unroll
    for (int kc = 0; kc < 6; ++kc) {
        #pragma unroll
        for (int ct = 0; ct < 6; ++ct) {
            bf16x8 bfr = *(const bf16x8*)&Bt[(ct * 16 + l16) * 200 + kc * 32 + quad * 8];
            acc[ct] = MFMA16(afr[kc], bfr, acc[ct]);
        }
    }
    int token0 = mtile * 64 + wv * 16 + quad * 4;
    #pragma unroll
    for (int ct = 0; ct < 6; ++ct) {
        int c = nblk * 96 + ct * 16 + l16;
        float bp = bproj[c];
        #pragma unroll
        for (int r = 0; r < 4; ++r)
            out[(token0 + r) * 192 + c] = acc[ct][r] + bp;
    }
}

// ---------------- launch ----------------
extern "C" void kernel_launch(void* const* d_in, const int* in_sizes, int n_in,
                              void* d_out, int out_size, void* d_ws, size_t ws_size,
                              hipStream_t stream) {
    const float* x     = (const float*)d_in[0];
    const float* mask  = (const float*)d_in[1];
    const float* wqkv  = (const float*)d_in[2];
    const float* wproj = (const float*)d_in[3];
    const float* bproj = (const float*)d_in[4];
    const float* btab  = (const float*)d_in[5];
    float* out = (float*)d_out;

    char* ws = (char*)d_ws;
    // ws layout (bytes):
    unsigned short* Ob     = (unsigned short*)(ws + 0);            // 53,084,160
    unsigned short* qb     = (unsigned short*)(ws + 53084160);     // 53,084,160
    unsigned short* kb     = (unsigned short*)(ws + 106168320);    // 53,084,160
    unsigned short* vtb    = (unsigned short*)(ws + 159252480);    // 53,084,160
    unsigned short* biasR  = (unsigned short*)(ws + 212336640);    // 17,694,720
    unsigned short* maskR  = (unsigned short*)(ws + 230031360);    // 44,236,800
    unsigned short* wqkvT  = (unsigned short*)(ws + 274268160);    //    221,184
    unsigned short* wprojT = (unsigned short*)(ws + 274489344);    //     73,728
    // total: 274,563,072 bytes

    prep_weights<<<576, 256, 0, stream>>>(wqkv, wproj, wqkvT, wprojT);
    prep_biasR<<<34560, 256, 0, stream>>>(btab, biasR);
    prep_maskR<<<8640, 256, 0, stream>>>(mask, maskR);
    qkv_gemm<<<12960, 256, 0, stream>>>(x, wqkvT, qb, kb, vtb);
    attn<<<5760, 192, 0, stream>>>(qb, kb, vtb, biasR, maskR, Ob);
    out_gemm<<<4320, 256, 0, stream>>>(Ob, wprojT, bproj, out);
}